// Round 2
// baseline (1067.129 us; speedup 1.0000x reference)
//
#include <hip/hip_runtime.h>

// ---------------------------------------------------------------------------
// QuantMLP: fake-quant MLP (up/gate 4-bit weights + silu + 8-bit act quant +
// down proj). fp16 MFMA pipeline (fp16 over bf16: 4x finer mantissa keeps
// 8-bit-quant boundary noise ~0.03 vs threshold 0.069).
// Shapes: T=8192 tokens, H=2048, I=5632.
//
// Workspace budget (suspected 256 MiB cap -> r1 core dump at 287 MiB):
//   d_ws : Wq_ug(46.1) + Wq_d(23.1) + C1(184.5) = 253.76 MiB
//   d_out: doubles as xh (fp16 x, 33.5 MiB) until GEMM2 overwrites it.
//          Legal: xh only read by GEMM1; GEMM2 reads C1/Wq_d, writes out.
// ---------------------------------------------------------------------------

#define DEVI __device__ __forceinline__

typedef _Float16 half8 __attribute__((ext_vector_type(8)));
typedef _Float16 half4v __attribute__((ext_vector_type(4)));
typedef float floatx4 __attribute__((ext_vector_type(4)));

static constexpr int T_TOK = 8192;   // B*S
static constexpr int H_DIM = 2048;
static constexpr int I_DIM = 5632;
static constexpr int N1 = 2 * I_DIM; // 11264 (gate | up)

DEVI void load16_lds(const _Float16* g, _Float16* l) {
    __builtin_amdgcn_global_load_lds(
        (const __attribute__((address_space(1))) unsigned int*)g,
        (__attribute__((address_space(3))) unsigned int*)l,
        16 /*bytes*/, 0 /*offset*/, 0 /*aux*/);
}

DEVI float block_amax_256(float v, float* sbuf) {
    #pragma unroll
    for (int off = 32; off; off >>= 1)
        v = fmaxf(v, __shfl_xor(v, off, 64));
    if ((threadIdx.x & 63) == 0) sbuf[threadIdx.x >> 6] = v;
    __syncthreads();
    return fmaxf(fmaxf(sbuf[0], sbuf[1]), fmaxf(sbuf[2], sbuf[3]));
}

// --------------------------- weight fake-quant ------------------------------
// per-row symmetric: scale = max(amax/qmax, 1e-8); out = clip(rint(w/s),±q)*s
template <int EPT>
__global__ __launch_bounds__(256) void quant_rows_kernel(
    const float* __restrict__ in, _Float16* __restrict__ out,
    int cols, float qmax) {
    __shared__ float sbuf[4];
    const size_t row = blockIdx.x;
    const float* r = in + row * (size_t)cols;
    _Float16* o = out + row * (size_t)cols;
    float v[EPT];
    float amax = 0.f;
    #pragma unroll
    for (int j = 0; j < EPT; ++j) {
        v[j] = r[threadIdx.x + j * 256];
        amax = fmaxf(amax, fabsf(v[j]));
    }
    amax = block_amax_256(amax, sbuf);
    const float scale = fmaxf(amax / qmax, 1e-8f);
    #pragma unroll
    for (int j = 0; j < EPT; ++j) {
        float q = rintf(v[j] / scale);
        q = fminf(fmaxf(q, -qmax), qmax);
        o[threadIdx.x + j * 256] = (_Float16)(q * scale);
    }
}

// --------------------------- x cast fp32 -> fp16 ----------------------------
// (16-bit per-token fake-quant has step amax/65534 << fp16 ulp; skipped)
__global__ __launch_bounds__(256) void cast_x_kernel(
    const float* __restrict__ in, _Float16* __restrict__ out) {
    const size_t i = ((size_t)blockIdx.x * 256 + threadIdx.x) * 4;
    floatx4 f = *(const floatx4*)(in + i);
    half4v h;
    h.x = (_Float16)f.x; h.y = (_Float16)f.y;
    h.z = (_Float16)f.z; h.w = (_Float16)f.w;
    *(half4v*)(out + i) = h;
}

// --------------------------- GEMM (B-transposed) ----------------------------
// C[M,N] = A[M,K] * B[N,K]^T.  128x128 tile, BK=32, 256 thr (4 waves, 2x2),
// each wave 4x4 of 16x16x32 fp16 MFMA. global_load_lds width=16 staging.
template <typename OutT>
__global__ __launch_bounds__(256) void gemm_bt_kernel(
    const _Float16* __restrict__ A, const _Float16* __restrict__ B,
    OutT* __restrict__ C, int N, int K, int lda, int ldb, int ldc) {
    __shared__ _Float16 As[128 * 32];
    __shared__ _Float16 Bs[128 * 32];

    const int tid = threadIdx.x;
    const int lane = tid & 63;
    const int w = tid >> 6;
    const int wm = w >> 1, wn = w & 1;
    const int row0 = blockIdx.y * 128;
    const int col0 = blockIdx.x * 128;

    // staging: thread t -> 16B chunk; LDS flat offset t*16B (wave-uniform
    // base + lane*16 as global_load_lds requires; no padding!)
    const int sr = tid >> 2;          // 0..63
    const int sc = (tid & 3) * 8;     // 0,8,16,24
    const _Float16* Ag0 = A + (size_t)(row0 + sr) * lda + sc;
    const _Float16* Ag1 = Ag0 + (size_t)64 * lda;
    const _Float16* Bg0 = B + (size_t)(col0 + sr) * ldb + sc;
    const _Float16* Bg1 = Bg0 + (size_t)64 * ldb;
    _Float16* Al0 = As + tid * 8;
    _Float16* Al1 = As + 2048 + tid * 8;
    _Float16* Bl0 = Bs + tid * 8;
    _Float16* Bl1 = Bs + 2048 + tid * 8;

    floatx4 acc[4][4] = {};

    const int fr = (lane & 15);       // fragment row within 16
    const int kc = (lane >> 4) * 8;   // k chunk 0/8/16/24

    for (int k0 = 0; k0 < K; k0 += 32) {
        load16_lds(Ag0 + k0, Al0);
        load16_lds(Ag1 + k0, Al1);
        load16_lds(Bg0 + k0, Bl0);
        load16_lds(Bg1 + k0, Bl1);
        __syncthreads();  // drains vmcnt(0): LDS writes visible

        half8 af[4], bf[4];
        #pragma unroll
        for (int mi = 0; mi < 4; ++mi)
            af[mi] = *(const half8*)(As + (wm * 64 + mi * 16 + fr) * 32 + kc);
        #pragma unroll
        for (int ni = 0; ni < 4; ++ni)
            bf[ni] = *(const half8*)(Bs + (wn * 64 + ni * 16 + fr) * 32 + kc);
        #pragma unroll
        for (int mi = 0; mi < 4; ++mi)
            #pragma unroll
            for (int ni = 0; ni < 4; ++ni)
                acc[mi][ni] = __builtin_amdgcn_mfma_f32_16x16x32_f16(
                    af[mi], bf[ni], acc[mi][ni], 0, 0, 0);
        __syncthreads();  // before next overwrite
    }

    // epilogue: C/D layout col=lane&15, row=(lane>>4)*4+i (dtype-independent)
    const int er = row0 + wm * 64 + (lane >> 4) * 4;
    const int ec = col0 + wn * 64 + (lane & 15);
    #pragma unroll
    for (int mi = 0; mi < 4; ++mi) {
        #pragma unroll
        for (int i = 0; i < 4; ++i) {
            const size_t r = (size_t)(er + mi * 16 + i);
            #pragma unroll
            for (int ni = 0; ni < 4; ++ni)
                C[r * ldc + (ec + ni * 16)] = (OutT)acc[mi][ni][i];
        }
    }
}

// ------------------- fused silu * up + 8-bit per-token quant ----------------
// C1 row layout: [gate(5632) | up(5632)], stride N1. Result (fp16) overwrites
// the gate half -> becomes A of down-proj GEMM with lda=N1.
__global__ __launch_bounds__(256) void silu_mul_quant_kernel(
    _Float16* __restrict__ c1) {
    __shared__ float sbuf[4];
    const size_t t = blockIdx.x;
    _Float16* g = c1 + t * (size_t)N1;
    const _Float16* u = g + I_DIM;

    float m[22];
    float amax = 0.f;
    #pragma unroll
    for (int j = 0; j < 22; ++j) {
        const int i = threadIdx.x + j * 256;
        const float gv = (float)g[i];
        const float uv = (float)u[i];
        const float act = gv / (1.f + __expf(-gv));  // silu
        m[j] = act * uv;
        amax = fmaxf(amax, fabsf(m[j]));
    }
    amax = block_amax_256(amax, sbuf);
    const float scale = fmaxf(amax / 127.f, 1e-8f);
    #pragma unroll
    for (int j = 0; j < 22; ++j) {
        const int i = threadIdx.x + j * 256;
        float q = rintf(m[j] / scale);
        q = fminf(fmaxf(q, -127.f), 127.f);
        g[i] = (_Float16)(q * scale);
    }
}

// ---------------------------------------------------------------------------
extern "C" void kernel_launch(void* const* d_in, const int* in_sizes, int n_in,
                              void* d_out, int out_size, void* d_ws, size_t ws_size,
                              hipStream_t stream) {
    const float* x  = (const float*)d_in[0];   // [8192, 2048]
    const float* Wg = (const float*)d_in[1];   // [5632, 2048]
    const float* Wu = (const float*)d_in[2];   // [5632, 2048]
    const float* Wd = (const float*)d_in[3];   // [2048, 5632]
    float* out = (float*)d_out;                // [8192, 2048] = 64 MiB

    // --- workspace layout (253.76 MiB total; r1's 287 MiB core-dumped) ---
    char* ws = (char*)d_ws;
    const size_t SZ_WUG = (size_t)N1 * H_DIM * 2;     //  46,137,344
    const size_t SZ_WD  = (size_t)H_DIM * I_DIM * 2;  //  23,068,672
    _Float16* Wq_ug = (_Float16*)ws;                  // [11264,2048]
    _Float16* Wq_d  = (_Float16*)(ws + SZ_WUG);       // [2048,5632]
    _Float16* C1    = (_Float16*)(ws + SZ_WUG + SZ_WD); // [8192,11264] 184.5 MiB
    // xh lives in d_out (33.5 of 64 MiB); dead before GEMM2 writes out.
    _Float16* xh    = (_Float16*)d_out;               // [8192,2048]

    // 4-bit per-row weight quant (qmax=7) -> fp16
    quant_rows_kernel<8><<<I_DIM, 256, 0, stream>>>(Wg, Wq_ug, H_DIM, 7.f);
    quant_rows_kernel<8><<<I_DIM, 256, 0, stream>>>(
        Wu, Wq_ug + (size_t)I_DIM * H_DIM, H_DIM, 7.f);
    quant_rows_kernel<22><<<H_DIM, 256, 0, stream>>>(Wd, Wq_d, I_DIM, 7.f);

    // x -> fp16 (into d_out scratch region)
    cast_x_kernel<<<(T_TOK * H_DIM) / 1024, 256, 0, stream>>>(x, xh);

    // GEMM1: C1[8192, 11264] = xh * Wq_ug^T  (gate | up)
    gemm_bt_kernel<_Float16><<<dim3(N1 / 128, T_TOK / 128), 256, 0, stream>>>(
        xh, Wq_ug, C1, N1, H_DIM, H_DIM, H_DIM, N1);

    // silu(gate)*up -> 8-bit per-token fake-quant -> overwrite gate half
    silu_mul_quant_kernel<<<T_TOK, 256, 0, stream>>>(C1);

    // GEMM2: out[8192, 2048] = mulq * Wq_d^T   (A = C1 gate half, lda=N1)
    gemm_bt_kernel<float><<<dim3(H_DIM / 128, T_TOK / 128), 256, 0, stream>>>(
        C1, Wq_d, out, H_DIM, I_DIM, N1, I_DIM, H_DIM);
}

// Round 3
// 969.026 us; speedup vs baseline: 1.1012x; 1.1012x over previous
//
#include <hip/hip_runtime.h>

// ---------------------------------------------------------------------------
// QuantMLP r3: fp16 MFMA up/gate GEMM with FUSED silu*mul epilogue
// (interleaved gate/up weight rows, fp32 mul -> one fp16 rounding -> ~2x less
// 8-bit-quant boundary-flip noise than r2's 0.0664) + INT8 down-proj
// (qa[-127,127] x qw[-7,7] via mfma_i32_16x16x64_i8: exact integer GEMM,
// 2x MFMA rate, half traffic).
// Shapes: T=8192 tokens, H=2048, I=5632.
// Workspace: Wq_ug(46.1) + mulh(92.3) + qa(46.1) + Qw_d(11.5) + scales
//          = ~196.3 MiB (r2's 253.76 passed; r1's 287 crashed).
// d_out doubles as xh (fp16 x) until GEMM2 overwrites it.
// ---------------------------------------------------------------------------

#define DEVI __device__ __forceinline__

typedef _Float16 half8 __attribute__((ext_vector_type(8)));
typedef _Float16 half4v __attribute__((ext_vector_type(4)));
typedef float floatx4 __attribute__((ext_vector_type(4)));
typedef int int4v __attribute__((ext_vector_type(4)));
typedef signed char char8v __attribute__((ext_vector_type(8)));

static constexpr int T_TOK = 8192;   // B*S
static constexpr int H_DIM = 2048;
static constexpr int I_DIM = 5632;
static constexpr int N1 = 2 * I_DIM; // 11264 interleaved (gate|up per 64)

DEVI void load16_lds(const void* g, void* l) {
    __builtin_amdgcn_global_load_lds(
        (const __attribute__((address_space(1))) unsigned int*)g,
        (__attribute__((address_space(3))) unsigned int*)l,
        16 /*bytes*/, 0 /*offset*/, 0 /*aux*/);
}

DEVI float block_amax_256(float v, float* sbuf) {
    #pragma unroll
    for (int off = 32; off; off >>= 1)
        v = fmaxf(v, __shfl_xor(v, off, 64));
    if ((threadIdx.x & 63) == 0) sbuf[threadIdx.x >> 6] = v;
    __syncthreads();
    return fmaxf(fmaxf(sbuf[0], sbuf[1]), fmaxf(sbuf[2], sbuf[3]));
}

// ------------------------- init per-token amax ------------------------------
__global__ __launch_bounds__(256) void init_amax_kernel(int* __restrict__ a) {
    a[blockIdx.x * 256 + threadIdx.x] = 0;  // float 0.0 bit pattern
}

// ------------------ Wg/Wu 4-bit fake-quant, interleaved out -----------------
// out row for source row i: (i>>6)*128 + (i&63) + HALF*64  (HALF: 0=gate,1=up)
template <int HALF>
__global__ __launch_bounds__(256) void quant_ug_kernel(
    const float* __restrict__ in, _Float16* __restrict__ out) {
    __shared__ float sbuf[4];
    const int i = blockIdx.x;
    const int orow = ((i >> 6) * 128) + (i & 63) + HALF * 64;
    const float* r = in + (size_t)i * H_DIM;
    _Float16* o = out + (size_t)orow * H_DIM;
    float v[8];
    float amax = 0.f;
    #pragma unroll
    for (int j = 0; j < 8; ++j) {
        v[j] = r[threadIdx.x + j * 256];
        amax = fmaxf(amax, fabsf(v[j]));
    }
    amax = block_amax_256(amax, sbuf);
    const float scale = fmaxf(amax / 7.f, 1e-8f);
    #pragma unroll
    for (int j = 0; j < 8; ++j) {
        float q = rintf(v[j] / scale);
        q = fminf(fmaxf(q, -7.f), 7.f);
        o[threadIdx.x + j * 256] = (_Float16)(q * scale);
    }
}

// ------------------ Wd 4-bit quant -> int8 codes + scale --------------------
__global__ __launch_bounds__(256) void quant_wd_i8_kernel(
    const float* __restrict__ in, signed char* __restrict__ qw,
    float* __restrict__ sw) {
    __shared__ float sbuf[4];
    const size_t row = blockIdx.x;
    const float* r = in + row * (size_t)I_DIM;
    signed char* o = qw + row * (size_t)I_DIM;
    float v[22];
    float amax = 0.f;
    #pragma unroll
    for (int j = 0; j < 22; ++j) {
        v[j] = r[threadIdx.x + j * 256];
        amax = fmaxf(amax, fabsf(v[j]));
    }
    amax = block_amax_256(amax, sbuf);
    const float scale = fmaxf(amax / 7.f, 1e-8f);
    if (threadIdx.x == 0) sw[row] = scale;
    #pragma unroll
    for (int j = 0; j < 22; ++j) {
        float q = rintf(v[j] / scale);
        q = fminf(fmaxf(q, -7.f), 7.f);
        o[threadIdx.x + j * 256] = (signed char)q;
    }
}

// --------------------------- x cast fp32 -> fp16 ----------------------------
__global__ __launch_bounds__(256) void cast_x_kernel(
    const float* __restrict__ in, _Float16* __restrict__ out) {
    const size_t i = ((size_t)blockIdx.x * 256 + threadIdx.x) * 4;
    floatx4 f = *(const floatx4*)(in + i);
    half4v h;
    h.x = (_Float16)f.x; h.y = (_Float16)f.y;
    h.z = (_Float16)f.z; h.w = (_Float16)f.w;
    *(half4v*)(out + i) = h;
}

// ---------------- GEMM1 (fp16) + fused silu*mul + row amax ------------------
// C_tile[128 tokens x 128] where cols 0-63 = gate(i), 64-127 = up(i) for
// i = blk*64 + c. wn=0 waves stash gate acc in LDS (pad 68: 2-way only),
// wn=1 waves compute mul = silu(g)*u in fp32, store fp16, atomicMax rowmax.
__global__ __launch_bounds__(256) void gemm1_fused_kernel(
    const _Float16* __restrict__ A,   // xh [8192][2048]
    const _Float16* __restrict__ B,   // Wq_ug interleaved [11264][2048]
    _Float16* __restrict__ mulh,      // [8192][5632]
    int* __restrict__ amax_bits) {    // [8192], pre-zeroed
    __shared__ _Float16 As[128 * 32];
    __shared__ _Float16 Bs[128 * 32];
    __shared__ float gbuf[128 * 68];  // +4 pad: write/read 2-way max

    const int tid = threadIdx.x;
    const int lane = tid & 63;
    const int w = tid >> 6;
    const int wm = w >> 1, wn = w & 1;
    const int row0 = blockIdx.y * 128;
    const int col0 = blockIdx.x * 128;

    const int sr = tid >> 2;
    const int sc = (tid & 3) * 8;
    const _Float16* Ag0 = A + (size_t)(row0 + sr) * H_DIM + sc;
    const _Float16* Ag1 = Ag0 + (size_t)64 * H_DIM;
    const _Float16* Bg0 = B + (size_t)(col0 + sr) * H_DIM + sc;
    const _Float16* Bg1 = Bg0 + (size_t)64 * H_DIM;
    _Float16* Al0 = As + tid * 8;
    _Float16* Al1 = As + 2048 + tid * 8;
    _Float16* Bl0 = Bs + tid * 8;
    _Float16* Bl1 = Bs + 2048 + tid * 8;

    floatx4 acc[4][4] = {};
    const int fr = (lane & 15);
    const int kc = (lane >> 4) * 8;

    for (int k0 = 0; k0 < H_DIM; k0 += 32) {
        load16_lds(Ag0 + k0, Al0);
        load16_lds(Ag1 + k0, Al1);
        load16_lds(Bg0 + k0, Bl0);
        load16_lds(Bg1 + k0, Bl1);
        __syncthreads();
        half8 af[4], bf[4];
        #pragma unroll
        for (int mi = 0; mi < 4; ++mi)
            af[mi] = *(const half8*)(As + (wm * 64 + mi * 16 + fr) * 32 + kc);
        #pragma unroll
        for (int ni = 0; ni < 4; ++ni)
            bf[ni] = *(const half8*)(Bs + (wn * 64 + ni * 16 + fr) * 32 + kc);
        #pragma unroll
        for (int mi = 0; mi < 4; ++mi)
            #pragma unroll
            for (int ni = 0; ni < 4; ++ni)
                acc[mi][ni] = __builtin_amdgcn_mfma_f32_16x16x32_f16(
                    af[mi], bf[ni], acc[mi][ni], 0, 0, 0);
        __syncthreads();
    }

    // ---- fused epilogue ----
    const int er = wm * 64 + (lane >> 4) * 4;  // local token row base
    const int ec = lane & 15;                  // local col base (within 64)
    if (wn == 0) {  // gate waves -> LDS
        #pragma unroll
        for (int mi = 0; mi < 4; ++mi)
            #pragma unroll
            for (int i = 0; i < 4; ++i)
                #pragma unroll
                for (int ni = 0; ni < 4; ++ni)
                    gbuf[(er + mi * 16 + i) * 68 + ec + ni * 16] =
                        acc[mi][ni][i];
    }
    __syncthreads();
    if (wn == 1) {  // up waves: mul = silu(g)*u, store fp16, rowmax atomic
        #pragma unroll
        for (int mi = 0; mi < 4; ++mi) {
            #pragma unroll
            for (int i = 0; i < 4; ++i) {
                const int r = er + mi * 16 + i;
                float rmax = 0.f, mv[4];
                #pragma unroll
                for (int ni = 0; ni < 4; ++ni) {
                    const float g = gbuf[r * 68 + ec + ni * 16];
                    const float u = acc[mi][ni][i];
                    const float m = g / (1.f + expf(-g)) * u;  // silu(g)*u
                    mv[ni] = m;
                    rmax = fmaxf(rmax, fabsf(m));
                }
                _Float16* mrow =
                    mulh + (size_t)(row0 + r) * I_DIM + blockIdx.x * 64 + ec;
                #pragma unroll
                for (int ni = 0; ni < 4; ++ni)
                    mrow[ni * 16] = (_Float16)mv[ni];
                // reduce over the 16-lane col group (xor 1,2,4,8 stay in-group)
                #pragma unroll
                for (int off = 1; off < 16; off <<= 1)
                    rmax = fmaxf(rmax, __shfl_xor(rmax, off, 64));
                if (ec == 0)
                    atomicMax(&amax_bits[row0 + r], __float_as_int(rmax));
            }
        }
    }
}

// ---------------- per-token 8-bit quant: fp16 mul -> int8 codes -------------
__global__ __launch_bounds__(256) void act_quant_kernel(
    const _Float16* __restrict__ mulh, const int* __restrict__ amax_bits,
    signed char* __restrict__ qa, float* __restrict__ sa) {
    const size_t t = blockIdx.x;
    const float amax = __int_as_float(amax_bits[t]);
    const float s = fmaxf(amax / 127.f, 1e-8f);
    if (threadIdx.x == 0) sa[t] = s;
    const float rs = 1.f / s;
    const _Float16* mrow = mulh + t * I_DIM;
    signed char* qrow = qa + t * I_DIM;
    for (int c = threadIdx.x; c < I_DIM / 8; c += 256) {
        half8 v = *(const half8*)(mrow + c * 8);
        char8v q;
        #pragma unroll
        for (int j = 0; j < 8; ++j) {
            float f = rintf((float)v[j] * rs);
            f = fminf(fmaxf(f, -127.f), 127.f);
            q[j] = (signed char)f;
        }
        *(char8v*)(qrow + c * 8) = q;
    }
}

// --------------------- GEMM2: int8 down-proj (exact) ------------------------
// out[t][o] = sa[t]*sw[o] * sum_i qa[t][i]*qw[o][i], mfma_i32_16x16x64_i8.
__global__ __launch_bounds__(256) void gemm2_i8_kernel(
    const signed char* __restrict__ A,  // qa [8192][5632]
    const signed char* __restrict__ B,  // Qw_d [2048][5632]
    const float* __restrict__ sa, const float* __restrict__ sw,
    float* __restrict__ C) {            // [8192][2048]
    __shared__ __align__(16) signed char As[128 * 64];
    __shared__ __align__(16) signed char Bs[128 * 64];

    const int tid = threadIdx.x;
    const int lane = tid & 63;
    const int w = tid >> 6;
    const int wm = w >> 1, wn = w & 1;
    const int row0 = blockIdx.y * 128;
    const int col0 = blockIdx.x * 128;

    const int sr = tid >> 2;
    const int sc = (tid & 3) * 16;        // 16 int8 per thread
    const signed char* Ag0 = A + (size_t)(row0 + sr) * I_DIM + sc;
    const signed char* Ag1 = Ag0 + (size_t)64 * I_DIM;
    const signed char* Bg0 = B + (size_t)(col0 + sr) * I_DIM + sc;
    const signed char* Bg1 = Bg0 + (size_t)64 * I_DIM;
    signed char* Al0 = As + tid * 16;
    signed char* Al1 = As + 4096 + tid * 16;
    signed char* Bl0 = Bs + tid * 16;
    signed char* Bl1 = Bs + 4096 + tid * 16;

    int4v acc[4][4] = {};
    const int fr = (lane & 15);
    const int kc = (lane >> 4) * 16;      // byte offset in 64B row

    for (int k0 = 0; k0 < I_DIM; k0 += 64) {
        load16_lds(Ag0 + k0, Al0);
        load16_lds(Ag1 + k0, Al1);
        load16_lds(Bg0 + k0, Bl0);
        load16_lds(Bg1 + k0, Bl1);
        __syncthreads();
        int4v af[4], bf[4];
        #pragma unroll
        for (int mi = 0; mi < 4; ++mi)
            af[mi] = *(const int4v*)(As + (wm * 64 + mi * 16 + fr) * 64 + kc);
        #pragma unroll
        for (int ni = 0; ni < 4; ++ni)
            bf[ni] = *(const int4v*)(Bs + (wn * 64 + ni * 16 + fr) * 64 + kc);
        #pragma unroll
        for (int mi = 0; mi < 4; ++mi)
            #pragma unroll
            for (int ni = 0; ni < 4; ++ni)
                acc[mi][ni] = __builtin_amdgcn_mfma_i32_16x16x64_i8(
                    af[mi], bf[ni], acc[mi][ni], 0, 0, 0);
        __syncthreads();
    }

    const int er = row0 + wm * 64 + (lane >> 4) * 4;
    const int ec = col0 + wn * 64 + (lane & 15);
    #pragma unroll
    for (int mi = 0; mi < 4; ++mi) {
        #pragma unroll
        for (int i = 0; i < 4; ++i) {
            const int r = er + mi * 16 + i;
            const float s_r = sa[r];
            #pragma unroll
            for (int ni = 0; ni < 4; ++ni) {
                const int c = ec + ni * 16;
                C[(size_t)r * H_DIM + c] = (float)acc[mi][ni][i] * s_r * sw[c];
            }
        }
    }
}

// ---------------------------------------------------------------------------
extern "C" void kernel_launch(void* const* d_in, const int* in_sizes, int n_in,
                              void* d_out, int out_size, void* d_ws, size_t ws_size,
                              hipStream_t stream) {
    const float* x  = (const float*)d_in[0];   // [8192, 2048]
    const float* Wg = (const float*)d_in[1];   // [5632, 2048]
    const float* Wu = (const float*)d_in[2];   // [5632, 2048]
    const float* Wd = (const float*)d_in[3];   // [2048, 5632]
    float* out = (float*)d_out;                // [8192, 2048] = 64 MiB

    char* ws = (char*)d_ws;
    const size_t SZ_WUG  = (size_t)N1 * H_DIM * 2;     // 46,137,344
    const size_t SZ_MULH = (size_t)T_TOK * I_DIM * 2;  // 92,274,688
    const size_t SZ_QA   = (size_t)T_TOK * I_DIM;      // 46,137,344
    const size_t SZ_QWD  = (size_t)H_DIM * I_DIM;      // 11,534,336
    _Float16*    Wq_ug = (_Float16*)ws;
    _Float16*    mulh  = (_Float16*)(ws + SZ_WUG);
    signed char* qa    = (signed char*)(ws + SZ_WUG + SZ_MULH);
    signed char* Qw_d  = (signed char*)(ws + SZ_WUG + SZ_MULH + SZ_QA);
    char* tail = ws + SZ_WUG + SZ_MULH + SZ_QA + SZ_QWD;
    float* sw        = (float*)tail;                    // [2048]
    float* sa        = (float*)(tail + 8192);           // [8192]
    int*   amax_bits = (int*)(tail + 8192 + 32768);     // [8192]
    // total: ~196.3 MiB
    _Float16* xh = (_Float16*)d_out;  // x fp16; dead before GEMM2 writes out

    init_amax_kernel<<<T_TOK / 256, 256, 0, stream>>>(amax_bits);
    quant_ug_kernel<0><<<I_DIM, 256, 0, stream>>>(Wg, Wq_ug);
    quant_ug_kernel<1><<<I_DIM, 256, 0, stream>>>(Wu, Wq_ug);
    quant_wd_i8_kernel<<<H_DIM, 256, 0, stream>>>(Wd, Qw_d, sw);
    cast_x_kernel<<<(T_TOK * H_DIM) / 1024, 256, 0, stream>>>(x, xh);

    gemm1_fused_kernel<<<dim3(N1 / 128, T_TOK / 128), 256, 0, stream>>>(
        xh, Wq_ug, mulh, amax_bits);

    act_quant_kernel<<<T_TOK, 256, 0, stream>>>(mulh, amax_bits, qa, sa);

    gemm2_i8_kernel<<<dim3(H_DIM / 128, T_TOK / 128), 256, 0, stream>>>(
        qa, Qw_d, sa, sw, out);
}

// Round 4
// 835.820 us; speedup vs baseline: 1.2767x; 1.1594x over previous
//
#include <hip/hip_runtime.h>

// ---------------------------------------------------------------------------
// QuantMLP r4: gate/up interleaved at 16-row granularity so silu*mul fuses
// IN-REGISTER in GEMM1's epilogue (r3's 34KiB LDS gbuf cost 11pt occupancy:
// 51200B LDS -> 21% occ, MfmaUtil 25%, 670us vs r2's 557us). LDS back to
// 16KiB. INT8 down-proj via mfma_i32_16x16x64_i8 (exact integer GEMM).
// Arithmetic kept bitwise-identical to r3 (absmax 0.06640625 < 0.069).
// Shapes: T=8192 tokens, H=2048, I=5632.
// Workspace: Wq_ug(46.1) + mulh(92.3) + qa(46.1) + Qw_d(11.5) + scales
//          = ~196.3 MiB. d_out doubles as xh (fp16 x) until GEMM2 writes.
// ---------------------------------------------------------------------------

#define DEVI __device__ __forceinline__

typedef _Float16 half8 __attribute__((ext_vector_type(8)));
typedef _Float16 half4v __attribute__((ext_vector_type(4)));
typedef float floatx4 __attribute__((ext_vector_type(4)));
typedef int int4v __attribute__((ext_vector_type(4)));
typedef signed char char8v __attribute__((ext_vector_type(8)));

static constexpr int T_TOK = 8192;   // B*S
static constexpr int H_DIM = 2048;
static constexpr int I_DIM = 5632;
static constexpr int N1 = 2 * I_DIM; // 11264: interleaved [16 gate | 16 up]*

DEVI void load16_lds(const void* g, void* l) {
    __builtin_amdgcn_global_load_lds(
        (const __attribute__((address_space(1))) unsigned int*)g,
        (__attribute__((address_space(3))) unsigned int*)l,
        16 /*bytes*/, 0 /*offset*/, 0 /*aux*/);
}

DEVI float block_amax_256(float v, float* sbuf) {
    #pragma unroll
    for (int off = 32; off; off >>= 1)
        v = fmaxf(v, __shfl_xor(v, off, 64));
    if ((threadIdx.x & 63) == 0) sbuf[threadIdx.x >> 6] = v;
    __syncthreads();
    return fmaxf(fmaxf(sbuf[0], sbuf[1]), fmaxf(sbuf[2], sbuf[3]));
}

// ------------------------- init per-token amax ------------------------------
__global__ __launch_bounds__(256) void init_amax_kernel(int* __restrict__ a) {
    a[blockIdx.x * 256 + threadIdx.x] = 0;  // float 0.0 bit pattern
}

// ------------------ Wg/Wu 4-bit fake-quant, interleaved out -----------------
// source row i -> dest row (i>>4)*32 + HALF*16 + (i&15)  (HALF: 0=gate,1=up)
// => in any 32-row group: rows 0-15 gate(i-block), 16-31 up(same i-block).
template <int HALF>
__global__ __launch_bounds__(256) void quant_ug_kernel(
    const float* __restrict__ in, _Float16* __restrict__ out) {
    __shared__ float sbuf[4];
    const int i = blockIdx.x;
    const int orow = ((i >> 4) * 32) + HALF * 16 + (i & 15);
    const float* r = in + (size_t)i * H_DIM;
    _Float16* o = out + (size_t)orow * H_DIM;
    float v[8];
    float amax = 0.f;
    #pragma unroll
    for (int j = 0; j < 8; ++j) {
        v[j] = r[threadIdx.x + j * 256];
        amax = fmaxf(amax, fabsf(v[j]));
    }
    amax = block_amax_256(amax, sbuf);
    const float scale = fmaxf(amax / 7.f, 1e-8f);
    #pragma unroll
    for (int j = 0; j < 8; ++j) {
        float q = rintf(v[j] / scale);
        q = fminf(fmaxf(q, -7.f), 7.f);
        o[threadIdx.x + j * 256] = (_Float16)(q * scale);
    }
}

// ------------------ Wd 4-bit quant -> int8 codes + scale --------------------
__global__ __launch_bounds__(256) void quant_wd_i8_kernel(
    const float* __restrict__ in, signed char* __restrict__ qw,
    float* __restrict__ sw) {
    __shared__ float sbuf[4];
    const size_t row = blockIdx.x;
    const float* r = in + row * (size_t)I_DIM;
    signed char* o = qw + row * (size_t)I_DIM;
    float v[22];
    float amax = 0.f;
    #pragma unroll
    for (int j = 0; j < 22; ++j) {
        v[j] = r[threadIdx.x + j * 256];
        amax = fmaxf(amax, fabsf(v[j]));
    }
    amax = block_amax_256(amax, sbuf);
    const float scale = fmaxf(amax / 7.f, 1e-8f);
    if (threadIdx.x == 0) sw[row] = scale;
    #pragma unroll
    for (int j = 0; j < 22; ++j) {
        float q = rintf(v[j] / scale);
        q = fminf(fmaxf(q, -7.f), 7.f);
        o[threadIdx.x + j * 256] = (signed char)q;
    }
}

// --------------------------- x cast fp32 -> fp16 ----------------------------
__global__ __launch_bounds__(256) void cast_x_kernel(
    const float* __restrict__ in, _Float16* __restrict__ out) {
    const size_t i = ((size_t)blockIdx.x * 256 + threadIdx.x) * 4;
    floatx4 f = *(const floatx4*)(in + i);
    half4v h;
    h.x = (_Float16)f.x; h.y = (_Float16)f.y;
    h.z = (_Float16)f.z; h.w = (_Float16)f.w;
    *(half4v*)(out + i) = h;
}

// ---------------- GEMM1 (fp16) + in-register silu*mul + row amax ------------
// B rows interleaved per-16: wave fragment ni=0,2 are gate cols, ni=1,3 the
// matching up cols with the SAME lane->i mapping (col=lane&15). So
// mul = silu(acc[mi][2p])*acc[mi][2p+1] is lane-local. LDS = 16 KiB only.
__global__ __launch_bounds__(256) void gemm1_fused_kernel(
    const _Float16* __restrict__ A,   // xh [8192][2048]
    const _Float16* __restrict__ B,   // Wq_ug interleaved [11264][2048]
    _Float16* __restrict__ mulh,      // [8192][5632]
    int* __restrict__ amax_bits) {    // [8192], pre-zeroed
    __shared__ _Float16 As[128 * 32];
    __shared__ _Float16 Bs[128 * 32];

    const int tid = threadIdx.x;
    const int lane = tid & 63;
    const int w = tid >> 6;
    const int wm = w >> 1, wn = w & 1;
    const int row0 = blockIdx.y * 128;
    const int col0 = blockIdx.x * 128;

    const int sr = tid >> 2;
    const int sc = (tid & 3) * 8;
    const _Float16* Ag0 = A + (size_t)(row0 + sr) * H_DIM + sc;
    const _Float16* Ag1 = Ag0 + (size_t)64 * H_DIM;
    const _Float16* Bg0 = B + (size_t)(col0 + sr) * H_DIM + sc;
    const _Float16* Bg1 = Bg0 + (size_t)64 * H_DIM;
    _Float16* Al0 = As + tid * 8;
    _Float16* Al1 = As + 2048 + tid * 8;
    _Float16* Bl0 = Bs + tid * 8;
    _Float16* Bl1 = Bs + 2048 + tid * 8;

    floatx4 acc[4][4] = {};
    const int fr = (lane & 15);
    const int kc = (lane >> 4) * 8;

    for (int k0 = 0; k0 < H_DIM; k0 += 32) {
        load16_lds(Ag0 + k0, Al0);
        load16_lds(Ag1 + k0, Al1);
        load16_lds(Bg0 + k0, Bl0);
        load16_lds(Bg1 + k0, Bl1);
        __syncthreads();
        half8 af[4], bf[4];
        #pragma unroll
        for (int mi = 0; mi < 4; ++mi)
            af[mi] = *(const half8*)(As + (wm * 64 + mi * 16 + fr) * 32 + kc);
        #pragma unroll
        for (int ni = 0; ni < 4; ++ni)
            bf[ni] = *(const half8*)(Bs + (wn * 64 + ni * 16 + fr) * 32 + kc);
        #pragma unroll
        for (int mi = 0; mi < 4; ++mi)
            #pragma unroll
            for (int ni = 0; ni < 4; ++ni)
                acc[mi][ni] = __builtin_amdgcn_mfma_f32_16x16x32_f16(
                    af[mi], bf[ni], acc[mi][ni], 0, 0, 0);
        __syncthreads();
    }

    // ---- fused epilogue: i = blockIdx.x*64 + wn*32 + p*16 + (lane&15) ----
    const int lr = wm * 64 + (lane >> 4) * 4;   // local token row (+mi*16+i)
    const int lc = lane & 15;
    _Float16* mbase = mulh + (size_t)blockIdx.x * 64 + wn * 32 + lc;
    #pragma unroll
    for (int mi = 0; mi < 4; ++mi) {
        #pragma unroll
        for (int i = 0; i < 4; ++i) {
            const int r = row0 + lr + mi * 16 + i;
            float rmax = 0.f;
            _Float16* mrow = mbase + (size_t)r * I_DIM;
            #pragma unroll
            for (int p = 0; p < 2; ++p) {
                const float g = acc[mi][2 * p][i];
                const float u = acc[mi][2 * p + 1][i];
                const float m = g / (1.f + expf(-g)) * u;  // silu(g)*u
                mrow[p * 16] = (_Float16)m;
                rmax = fmaxf(rmax, fabsf(m));
            }
            // reduce over the 16-lane quarter (xor 1,2,4,8 stay in-quarter)
            #pragma unroll
            for (int off = 1; off < 16; off <<= 1)
                rmax = fmaxf(rmax, __shfl_xor(rmax, off, 64));
            if (lc == 0)
                atomicMax(&amax_bits[r], __float_as_int(rmax));
        }
    }
}

// ---------------- per-token 8-bit quant: fp16 mul -> int8 codes -------------
__global__ __launch_bounds__(256) void act_quant_kernel(
    const _Float16* __restrict__ mulh, const int* __restrict__ amax_bits,
    signed char* __restrict__ qa, float* __restrict__ sa) {
    const size_t t = blockIdx.x;
    const float amax = __int_as_float(amax_bits[t]);
    const float s = fmaxf(amax / 127.f, 1e-8f);
    if (threadIdx.x == 0) sa[t] = s;
    const float rs = 1.f / s;
    const _Float16* mrow = mulh + t * I_DIM;
    signed char* qrow = qa + t * I_DIM;
    for (int c = threadIdx.x; c < I_DIM / 8; c += 256) {
        half8 v = *(const half8*)(mrow + c * 8);
        char8v q;
        #pragma unroll
        for (int j = 0; j < 8; ++j) {
            float f = rintf((float)v[j] * rs);
            f = fminf(fmaxf(f, -127.f), 127.f);
            q[j] = (signed char)f;
        }
        *(char8v*)(qrow + c * 8) = q;
    }
}

// --------------------- GEMM2: int8 down-proj (exact) ------------------------
// out[t][o] = sa[t]*sw[o] * sum_i qa[t][i]*qw[o][i], mfma_i32_16x16x64_i8.
__global__ __launch_bounds__(256) void gemm2_i8_kernel(
    const signed char* __restrict__ A,  // qa [8192][5632]
    const signed char* __restrict__ B,  // Qw_d [2048][5632]
    const float* __restrict__ sa, const float* __restrict__ sw,
    float* __restrict__ C) {            // [8192][2048]
    __shared__ __align__(16) signed char As[128 * 64];
    __shared__ __align__(16) signed char Bs[128 * 64];

    const int tid = threadIdx.x;
    const int lane = tid & 63;
    const int w = tid >> 6;
    const int wm = w >> 1, wn = w & 1;
    const int row0 = blockIdx.y * 128;
    const int col0 = blockIdx.x * 128;

    const int sr = tid >> 2;
    const int sc = (tid & 3) * 16;        // 16 int8 per thread
    const signed char* Ag0 = A + (size_t)(row0 + sr) * I_DIM + sc;
    const signed char* Ag1 = Ag0 + (size_t)64 * I_DIM;
    const signed char* Bg0 = B + (size_t)(col0 + sr) * I_DIM + sc;
    const signed char* Bg1 = Bg0 + (size_t)64 * I_DIM;
    signed char* Al0 = As + tid * 16;
    signed char* Al1 = As + 4096 + tid * 16;
    signed char* Bl0 = Bs + tid * 16;
    signed char* Bl1 = Bs + 4096 + tid * 16;

    int4v acc[4][4] = {};
    const int fr = (lane & 15);
    const int kc = (lane >> 4) * 16;      // byte offset in 64B row

    for (int k0 = 0; k0 < I_DIM; k0 += 64) {
        load16_lds(Ag0 + k0, Al0);
        load16_lds(Ag1 + k0, Al1);
        load16_lds(Bg0 + k0, Bl0);
        load16_lds(Bg1 + k0, Bl1);
        __syncthreads();
        int4v af[4], bf[4];
        #pragma unroll
        for (int mi = 0; mi < 4; ++mi)
            af[mi] = *(const int4v*)(As + (wm * 64 + mi * 16 + fr) * 64 + kc);
        #pragma unroll
        for (int ni = 0; ni < 4; ++ni)
            bf[ni] = *(const int4v*)(Bs + (wn * 64 + ni * 16 + fr) * 64 + kc);
        #pragma unroll
        for (int mi = 0; mi < 4; ++mi)
            #pragma unroll
            for (int ni = 0; ni < 4; ++ni)
                acc[mi][ni] = __builtin_amdgcn_mfma_i32_16x16x64_i8(
                    af[mi], bf[ni], acc[mi][ni], 0, 0, 0);
        __syncthreads();
    }

    const int er = row0 + wm * 64 + (lane >> 4) * 4;
    const int ec = col0 + wn * 64 + (lane & 15);
    #pragma unroll
    for (int mi = 0; mi < 4; ++mi) {
        #pragma unroll
        for (int i = 0; i < 4; ++i) {
            const int r = er + mi * 16 + i;
            const float s_r = sa[r];
            #pragma unroll
            for (int ni = 0; ni < 4; ++ni) {
                const int c = ec + ni * 16;
                C[(size_t)r * H_DIM + c] = (float)acc[mi][ni][i] * s_r * sw[c];
            }
        }
    }
}

// ---------------------------------------------------------------------------
extern "C" void kernel_launch(void* const* d_in, const int* in_sizes, int n_in,
                              void* d_out, int out_size, void* d_ws, size_t ws_size,
                              hipStream_t stream) {
    const float* x  = (const float*)d_in[0];   // [8192, 2048]
    const float* Wg = (const float*)d_in[1];   // [5632, 2048]
    const float* Wu = (const float*)d_in[2];   // [5632, 2048]
    const float* Wd = (const float*)d_in[3];   // [2048, 5632]
    float* out = (float*)d_out;                // [8192, 2048] = 64 MiB

    char* ws = (char*)d_ws;
    const size_t SZ_WUG  = (size_t)N1 * H_DIM * 2;     // 46,137,344
    const size_t SZ_MULH = (size_t)T_TOK * I_DIM * 2;  // 92,274,688
    const size_t SZ_QA   = (size_t)T_TOK * I_DIM;      // 46,137,344
    const size_t SZ_QWD  = (size_t)H_DIM * I_DIM;      // 11,534,336
    _Float16*    Wq_ug = (_Float16*)ws;
    _Float16*    mulh  = (_Float16*)(ws + SZ_WUG);
    signed char* qa    = (signed char*)(ws + SZ_WUG + SZ_MULH);
    signed char* Qw_d  = (signed char*)(ws + SZ_WUG + SZ_MULH + SZ_QA);
    char* tail = ws + SZ_WUG + SZ_MULH + SZ_QA + SZ_QWD;
    float* sw        = (float*)tail;                    // [2048]
    float* sa        = (float*)(tail + 8192);           // [8192]
    int*   amax_bits = (int*)(tail + 8192 + 32768);     // [8192]
    // total: ~196.3 MiB
    _Float16* xh = (_Float16*)d_out;  // x fp16; dead before GEMM2 writes out

    init_amax_kernel<<<T_TOK / 256, 256, 0, stream>>>(amax_bits);
    quant_ug_kernel<0><<<I_DIM, 256, 0, stream>>>(Wg, Wq_ug);
    quant_ug_kernel<1><<<I_DIM, 256, 0, stream>>>(Wu, Wq_ug);
    quant_wd_i8_kernel<<<H_DIM, 256, 0, stream>>>(Wd, Qw_d, sw);
    cast_x_kernel<<<(T_TOK * H_DIM) / 1024, 256, 0, stream>>>(x, xh);

    gemm1_fused_kernel<<<dim3(N1 / 128, T_TOK / 128), 256, 0, stream>>>(
        xh, Wq_ug, mulh, amax_bits);

    act_quant_kernel<<<T_TOK, 256, 0, stream>>>(mulh, amax_bits, qa, sa);

    gemm2_i8_kernel<<<dim3(H_DIM / 128, T_TOK / 128), 256, 0, stream>>>(
        qa, Qw_d, sa, sw, out);
}